// Round 14
// baseline (762.984 us; speedup 1.0000x reference)
//
#include <hip/hip_runtime.h>
#include <math.h>

// FastFourierConvolution: B=4, C=128, H=W=256. Cg=Cl=64, Ci=32.
// FU1: (B,32,256,256) -> rfft2 -> conv64x64+BN+relu -> herm irfft2
// FU2 (LFU): y_in[:,24:32] quadrant-stacked to (B,32,128,128), same pipeline, tiled 2x2.
// R14 (base R13 = 523.7us): final_fused prefetch deepened 2->4 channels per iteration
// (final_l both streams; final_g pass 1) using the conv_in-proven 4-deep idiom.
// Per-output fma order remains ci-ascending -> bit-identical. Weights stay scalar (SGPR).

#define PI2 6.283185307179586f

__device__ __forceinline__ void fma4(float4& a, float w, const float4& v) {
  a.x += w * v.x; a.y += w * v.y; a.z += w * v.z; a.w += w * v.w;
}
__device__ __forceinline__ float4 add4(const float4& a, const float4& b) {
  return make_float4(a.x + b.x, a.y + b.y, a.z + b.z, a.w + b.w);
}

// ---------------- FFT core: radix-2 DIT in LDS ----------------
template<int N, int LOG2N>
__device__ __forceinline__ void fft_stages(float* re, float* im, int tid, float sign) {
#pragma unroll
  for (int s = 1; s <= LOG2N; ++s) {
    __syncthreads();
    const int half = 1 << (s - 1);
    const int j = tid & (half - 1);
    const int i1 = ((tid >> (s - 1)) << s) + j;
    const int i2 = i1 + half;
    float ang = sign * (PI2 / (float)(1 << s)) * (float)j;
    float wr, wi;
    __sincosf(ang, &wi, &wr);
    float xr = re[i2], xi = im[i2];
    float vr = xr * wr - xi * wi;
    float vi = xr * wi + xi * wr;
    float ur = re[i1], ui = im[i1];
    re[i1] = ur + vr; im[i1] = ui + vi;
    re[i2] = ur - vr; im[i2] = ui - vi;
  }
  __syncthreads();
}

// ---------------- fused row rfft ----------------
// FU1: 2 real rows packed into 1 complex N=256 FFT (16384 blocks), Hermitian split.
// FU2 (LFU): N=128, 2 rows per block via 64-thread sub-groups.
__global__ void rfft_fused(const float* __restrict__ y_in,
                           float2* __restrict__ S1, float2* __restrict__ S2) {
  __shared__ float re[256], im[256];
  const int t = threadIdx.x;  // 128
  if (blockIdx.x < 16384) {
    const int pr = blockIdx.x;                 // rows 2pr, 2pr+1
    const float* p0 = y_in + (size_t)(2 * pr) * 256;
    const float* p1 = p0 + 256;
    for (int i = t; i < 256; i += 128) {
      int j = __brev((unsigned)i) >> 24;
      re[j] = p0[i];
      im[j] = p1[i];
    }
    fft_stages<256, 8>(re, im, t, -1.f);
    float2* q0 = S1 + (size_t)(2 * pr) * 129;
    float2* q1 = q0 + 129;
    for (int k = t; k <= 128; k += 128) {
      int nk = (256 - k) & 255;
      float zr = re[k], zi = im[k], zrn = re[nk], zin = im[nk];
      q0[k] = make_float2(0.5f * (zr + zrn), 0.5f * (zi - zin));
      q1[k] = make_float2(0.5f * (zi + zin), 0.5f * (zrn - zr));
    }
  } else {
    const int sub = t >> 6, t64 = t & 63;
    const int row = (blockIdx.x - 16384) * 2 + sub;   // 16384 LFU rows
    const int h2 = row & 127;
    const int c2 = (row >> 7) & 31;
    const int b  = row >> 12;
    const int q = c2 >> 3, ch = c2 & 7;
    const int hs = ((q >> 1) << 7) + h2;
    const int ws0 = (q & 1) << 7;
    const float* p = y_in + (((size_t)(b * 32 + 24 + ch) * 256 + hs) * 256 + ws0);
    float* r = &re[sub * 128];
    float* iv = &im[sub * 128];
    for (int i = t64; i < 128; i += 64) {
      int j = __brev((unsigned)i) >> 25;
      r[j] = p[i];
      iv[j] = 0.f;
    }
    fft_stages<128, 7>(r, iv, t64, -1.f);
    float2* qp = S2 + (size_t)row * 65;
    for (int k = t64; k <= 64; k += 64) qp[k] = make_float2(r[k], iv[k]);
  }
}

// ---------------- fused forward column FFT (flat [N][17] shared) ----------------
template<int N, int LOG2N>
__device__ __forceinline__ void cfft_cols_body(float2* __restrict__ data, int Wf, float sign,
                                               int tilesPerImg, int bid,
                                               float* __restrict__ re, float* __restrict__ im) {
  const int TW = 16;
  const int img = bid / tilesPerImg;
  const int k0 = (bid % tilesPerImg) * TW;
  const int cols = min(TW, Wf - k0);
  float2* base = data + (size_t)img * N * Wf + k0;
  const int t = threadIdx.x;
  const int c = t & (TW - 1);
  const int g = t >> 4;
  const bool act = (c < cols);
  for (int r = g; r < N; r += 16) {
    float2 v;
    if (act) v = base[(size_t)r * Wf + c];
    int j = __brev((unsigned)r) >> (32 - LOG2N);
    if (act) { re[j * 17 + c] = v.x; im[j * 17 + c] = v.y; }
  }
#pragma unroll
  for (int s = 1; s <= LOG2N; ++s) {
    __syncthreads();
    const int half = 1 << (s - 1);
    for (int bf = g; bf < N / 2; bf += 16) {
      if (!act) continue;
      const int j = bf & (half - 1);
      const int i1 = ((bf >> (s - 1)) << s) + j;
      const int i2 = i1 + half;
      float ang = sign * (PI2 / (float)(1 << s)) * (float)j;
      float wr, wi;
      __sincosf(ang, &wi, &wr);
      float xr = re[i2 * 17 + c], xi = im[i2 * 17 + c];
      float vr = xr * wr - xi * wi;
      float vi = xr * wi + xi * wr;
      float ur = re[i1 * 17 + c], ui = im[i1 * 17 + c];
      re[i1 * 17 + c] = ur + vr; im[i1 * 17 + c] = ui + vi;
      re[i2 * 17 + c] = ur - vr; im[i2 * 17 + c] = ui - vi;
    }
  }
  __syncthreads();
  for (int r = g; r < N; r += 16) {
    if (act) base[(size_t)r * Wf + c] = make_float2(re[r * 17 + c], im[r * 17 + c]);
  }
}

__global__ void cfft_cols_fused(float2* __restrict__ d1, float2* __restrict__ d2) {
  __shared__ float re[256 * 17], im[256 * 17];
  if (blockIdx.x < 1152)
    cfft_cols_body<256, 8>(d1, 129, -1.f, 9, blockIdx.x, re, im);
  else
    cfft_cols_body<128, 7>(d2, 65, -1.f, 5, blockIdx.x - 1152, re, im);
}

// ---------------- fused BN(finalize inlined)+relu+symmetrize + inverse column FFT --------
template<int N, int LOG2N>
__device__ __forceinline__ void cfft_inv_body(const float* __restrict__ Z,
                            const double* __restrict__ pb, const float* __restrict__ gamma,
                            const float* __restrict__ beta, int n,
                            float2* __restrict__ T, int Wf, int tilesPerImg, int chs, int bid,
                            float* __restrict__ re, float* __restrict__ im) {
  const int TW = 16;
  const int img = bid / tilesPerImg;    // b*32 + cc
  const int b = img >> 5, cc = img & 31;
  const int k0 = (bid % tilesPerImg) * TW;
  const int cols = min(TW, Wf - k0);
  const int t = threadIdx.x;
  const int c = t & (TW - 1);
  const int g = t >> 4;
  const bool act = (c < cols);
  const int kk = k0 + c;
  // inlined bn_finalize: sum the 32 per-slice partials in the exact order the old kernel used
  double s_r = 0.0, q_r = 0.0, s_i = 0.0, q_i = 0.0;
  for (int i = 0; i < 32; ++i) {
    s_r += pb[2 * (cc * 32 + i)];
    q_r += pb[2 * (cc * 32 + i) + 1];
    s_i += pb[2 * ((cc + 32) * 32 + i)];
    q_i += pb[2 * ((cc + 32) * 32 + i) + 1];
  }
  double mu_r = s_r / (double)n, var_r = q_r / (double)n - mu_r * mu_r;
  double mu_i = s_i / (double)n, var_i = q_i / (double)n - mu_i * mu_i;
  float rs_r = (float)(1.0 / sqrt(var_r + 1e-5));
  float rs_i = (float)(1.0 / sqrt(var_i + 1e-5));
  const float scr = gamma[cc] * rs_r;
  const float sfr = beta[cc] - (float)mu_r * scr;
  const float sci = gamma[cc + 32] * rs_i;
  const float sfi = beta[cc + 32] - (float)mu_i * sci;
  const float* Zr = Z + (size_t)cc * chs + (size_t)b * N * Wf;
  const float* Zi = Z + (size_t)(cc + 32) * chs + (size_t)b * N * Wf;
  const bool edge = (kk == 0 || kk == Wf - 1);
  for (int r = g; r < N; r += 16) {
    float vr = 0.f, vi = 0.f;
    if (act) {
      size_t p = (size_t)r * Wf + kk;
      float yr = fmaxf(Zr[p] * scr + sfr, 0.f);
      float yi = fmaxf(Zi[p] * sci + sfi, 0.f);
      if (edge) {
        int rm = (N - r) & (N - 1);
        size_t pm = (size_t)rm * Wf + kk;
        float yr2 = fmaxf(Zr[pm] * scr + sfr, 0.f);
        float yi2 = fmaxf(Zi[pm] * sci + sfi, 0.f);
        yr = 0.5f * (yr + yr2);
        yi = 0.5f * (yi - yi2);
      }
      vr = yr; vi = yi;
    }
    int j = __brev((unsigned)r) >> (32 - LOG2N);
    if (act) { re[j * 17 + c] = vr; im[j * 17 + c] = vi; }
  }
#pragma unroll
  for (int s = 1; s <= LOG2N; ++s) {
    __syncthreads();
    const int half = 1 << (s - 1);
    for (int bf = g; bf < N / 2; bf += 16) {
      if (!act) continue;
      const int jq = bf & (half - 1);
      const int i1 = ((bf >> (s - 1)) << s) + jq;
      const int i2 = i1 + half;
      float ang = (PI2 / (float)(1 << s)) * (float)jq;
      float wr, wi;
      __sincosf(ang, &wi, &wr);
      float xr = re[i2 * 17 + c], xi = im[i2 * 17 + c];
      float pr = xr * wr - xi * wi;
      float pi = xr * wi + xi * wr;
      float ur = re[i1 * 17 + c], ui = im[i1 * 17 + c];
      re[i1 * 17 + c] = ur + pr; im[i1 * 17 + c] = ui + pi;
      re[i2 * 17 + c] = ur - pr; im[i2 * 17 + c] = ui - pi;
    }
  }
  __syncthreads();
  float2* base = T + (size_t)img * N * Wf + k0;
  for (int r = g; r < N; r += 16)
    if (act) base[(size_t)r * Wf + c] = make_float2(re[r * 17 + c], im[r * 17 + c]);
}

__global__ void cfft_inv_fused(const float* __restrict__ Z1, const double* __restrict__ pb1,
                               const float* __restrict__ g1, const float* __restrict__ be1,
                               float2* __restrict__ T1,
                               const float* __restrict__ Z2, const double* __restrict__ pb2,
                               const float* __restrict__ g2, const float* __restrict__ be2,
                               float2* __restrict__ T2) {
  __shared__ float re[256 * 17], im[256 * 17];
  if (blockIdx.x < 1152)
    cfft_inv_body<256, 8>(Z1, pb1, g1, be1, 132096, T1, 129, 9, 132096, blockIdx.x, re, im);
  else
    cfft_inv_body<128, 7>(Z2, pb2, g2, be2, 33280, T2, 65, 5, 33280, blockIdx.x - 1152, re, im);
}

// ---------------- fused row irfft ----------------
// FU1: 2 Hermitian spectra packed into 1 complex inverse N=256 FFT (16384 blocks).
// FU2: N=128, 2 rows per block via 64-thread sub-groups.
__global__ void irfft_fused(const float2* __restrict__ T1, float* __restrict__ y_g,
                            const float2* __restrict__ T2, float* __restrict__ y2) {
  __shared__ float re[256], im[256];
  const int t = threadIdx.x;  // 128
  if (blockIdx.x < 16384) {
    const int pr = blockIdx.x;                 // rows 2pr, 2pr+1
    const float2* p0 = T1 + (size_t)(2 * pr) * 129;
    const float2* p1 = p0 + 129;
    for (int i = t; i < 256; i += 128) {
      float zr, zi;
      if (i <= 128) {
        float2 A = p0[i], Bv = p1[i];
        zr = A.x - Bv.y; zi = A.y + Bv.x;          // Z = A + iB
      } else {
        int nk = 256 - i;
        float2 A = p0[nk], Bv = p1[nk];
        zr = A.x + Bv.y; zi = Bv.x - A.y;          // Z = conj(A) + i conj(B)
      }
      int j = __brev((unsigned)i) >> 24;
      re[j] = zr; im[j] = zi;
    }
    fft_stages<256, 8>(re, im, t, 1.f);
    float* q0 = y_g + (size_t)(2 * pr) * 256;
    float* q1 = q0 + 256;
    for (int i = t; i < 256; i += 128) {
      q0[i] = re[i] * (1.f / 65536.f);
      q1[i] = im[i] * (1.f / 65536.f);
    }
  } else {
    const int sub = t >> 6, t64 = t & 63;
    const int row = (blockIdx.x - 16384) * 2 + sub;   // 16384 FU2 rows
    const float2* p = T2 + (size_t)row * 65;
    float* r = &re[sub * 128];
    float* iv = &im[sub * 128];
    for (int i = t64; i < 128; i += 64) {
      float2 v;
      if (i <= 64) v = p[i];
      else { v = p[128 - i]; v.y = -v.y; }
      int j = __brev((unsigned)i) >> 25;
      r[j] = v.x; iv[j] = v.y;
    }
    fft_stages<128, 7>(r, iv, t64, 1.f);
    float* q = y2 + (size_t)row * 128;
    for (int i = t64; i < 128; i += 64) q[i] = r[i] * (1.f / 16384.f);
  }
}

// ---------------- y_in = w_in(32x64) @ x[:, :64] + b_in: scalar weights, zero LDS --------
__global__ __launch_bounds__(256, 4) void conv_in_v(const float* __restrict__ x,
                          const float* __restrict__ wT,   // inT[ci*32+o]
                          const float* __restrict__ bias, float* __restrict__ y) {
  const int t = threadIdx.x;
  const int og = __builtin_amdgcn_readfirstlane(t >> 6);   // 0..3, wave-uniform
  const int p4 = blockIdx.x * 64 + (t & 63);   // 65536 float4-pixels
  const int hw4 = p4 & 16383;
  const int b = p4 >> 14;
  const float4* xb = (const float4*)x + (size_t)b * 128 * 16384 + hw4;
  float4 acc[8];
#pragma unroll
  for (int o = 0; o < 8; ++o) { float bv = bias[og * 8 + o]; acc[o] = make_float4(bv, bv, bv, bv); }
  float4 n0 = xb[0], n1 = xb[16384], n2 = xb[2 * 16384], n3 = xb[3 * 16384];
  for (int ci = 0; ci < 64; ci += 4) {
    float4 c0 = n0, c1 = n1, c2 = n2, c3 = n3;
    if (ci < 60) {
      const float4* np = xb + (size_t)(ci + 4) * 16384;
      n0 = np[0]; n1 = np[16384]; n2 = np[2 * 16384]; n3 = np[3 * 16384];
    }
#pragma unroll
    for (int k = 0; k < 4; ++k) {
      float4 v = (k == 0) ? c0 : (k == 1) ? c1 : (k == 2) ? c2 : c3;
      const float4* w4p = (const float4*)&wT[(ci + k) * 32 + og * 8];
      float4 a = w4p[0], c = w4p[1];
      fma4(acc[0], a.x, v); fma4(acc[1], a.y, v); fma4(acc[2], a.z, v); fma4(acc[3], a.w, v);
      fma4(acc[4], c.x, v); fma4(acc[5], c.y, v); fma4(acc[6], c.z, v); fma4(acc[7], c.w, v);
    }
  }
  float4* yb = (float4*)y + (size_t)(b * 32 + og * 8) * 16384 + hw4;
#pragma unroll
  for (int o = 0; o < 8; ++o) yb[(size_t)o * 16384] = acc[o];
}

// ---------------- spectral conv: scalar weights, zero LDS ----------------
template<int B_, int H_, int Wf_>
__device__ __forceinline__ void conv_spec_body(const float4* __restrict__ S4,
                            const float* __restrict__ wT,   // [ci*64+o], ci incl imag rows
                            const float* __restrict__ bias,
                            float2* __restrict__ Z2, int bid, int og, int t) {
  constexpr int PP = H_ * Wf_ / 2;      // complex pairs per (b,ci) plane
  constexpr int CHS2 = B_ * PP;         // pairs per out-channel
  const int j2 = bid * 128 + (t & 127);         // global pair index
  const int b = j2 / PP;
  const int jp = j2 - b * PP;
  float2 acc[32];
#pragma unroll
  for (int o = 0; o < 32; ++o) { float bv = bias[og * 32 + o]; acc[o] = make_float2(bv, bv); }
  const float4* sp = S4 + (size_t)(b * 32) * PP + jp;
  float4 nv = sp[0];
  for (int ci = 0; ci < 32; ++ci) {
    float4 sv = nv;                      // two complex: (x,y) (z,w)
    if (ci < 31) nv = sp[(size_t)(ci + 1) * PP];
    const float4* wr4 = (const float4*)&wT[ci * 64 + og * 32];
    const float4* wi4 = (const float4*)&wT[(ci + 32) * 64 + og * 32];
#pragma unroll
    for (int o4 = 0; o4 < 8; ++o4) {
      float4 a = wr4[o4], c = wi4[o4];
      acc[4 * o4 + 0].x += a.x * sv.x + c.x * sv.y;  acc[4 * o4 + 0].y += a.x * sv.z + c.x * sv.w;
      acc[4 * o4 + 1].x += a.y * sv.x + c.y * sv.y;  acc[4 * o4 + 1].y += a.y * sv.z + c.y * sv.w;
      acc[4 * o4 + 2].x += a.z * sv.x + c.z * sv.y;  acc[4 * o4 + 2].y += a.z * sv.z + c.z * sv.w;
      acc[4 * o4 + 3].x += a.w * sv.x + c.w * sv.y;  acc[4 * o4 + 3].y += a.w * sv.z + c.w * sv.w;
    }
  }
#pragma unroll
  for (int o = 0; o < 32; ++o) Z2[(size_t)(og * 32 + o) * CHS2 + j2] = acc[o];
}

__global__ __launch_bounds__(256, 4) void conv_spec_fused(
    const float4* __restrict__ S1, const float* __restrict__ w1T, const float* __restrict__ b1,
    float2* __restrict__ Z1,
    const float4* __restrict__ S2, const float* __restrict__ w2T, const float* __restrict__ b2,
    float2* __restrict__ Z2) {
  const int t = threadIdx.x;
  const int og = __builtin_amdgcn_readfirstlane(t >> 7);   // 0/1, wave-uniform
  if (blockIdx.x < 516)
    conv_spec_body<4, 256, 129>(S1, w1T, b1, Z1, blockIdx.x, og, t);
  else
    conv_spec_body<4, 128, 65>(S2, w2T, b2, Z2, blockIdx.x - 516, og, t);
}

// ---------------- BN stats fused (FU1: 2048 blocks, FU2: 2048 blocks) ----------------
__global__ void bn_stats_fused(const float* __restrict__ Z1, const float* __restrict__ Z2,
                               double* __restrict__ pb1, double* __restrict__ pb2) {
  int bid = blockIdx.x;
  const float* Z; double* pb; int chunk;
  if (bid < 2048) { Z = Z1; pb = pb1; chunk = 4128; }
  else { bid -= 2048; Z = Z2; pb = pb2; chunk = 1040; }
  const int c = bid >> 5;
  const int sl = bid & 31;
  const float* p = Z + (size_t)c * ((size_t)chunk * 32) + (size_t)sl * chunk;
  double s = 0.0, s2 = 0.0;
  for (int i = threadIdx.x; i < chunk; i += 256) {
    float v = p[i];
    s += v;
    s2 += (double)v * (double)v;
  }
  __shared__ double sh[256], sh2[256];
  sh[threadIdx.x] = s; sh2[threadIdx.x] = s2;
  __syncthreads();
  for (int off = 128; off > 0; off >>= 1) {
    if (threadIdx.x < off) { sh[threadIdx.x] += sh[threadIdx.x + off]; sh2[threadIdx.x] += sh2[threadIdx.x + off]; }
    __syncthreads();
  }
  if (threadIdx.x == 0) { pb[2 * bid] = sh[0]; pb[2 * bid + 1] = sh2[0]; }
}

// ---------------- weight transpose for scalar-load kernels ----------------
// wT layout (floats): [0..4095] g2l_T, [4096..8191] local_T, [8192..10239] out_T,
// [10240..14335] l2g_T, [14336..16383] in_T[ci*32+o], [16384..20479] fu1_T[ci*64+o],
// [20480..24575] fu2_T[ci*64+o].
__global__ void prep_weights(const float* __restrict__ w_g2l, const float* __restrict__ w_local,
                             const float* __restrict__ w_out, const float* __restrict__ w_l2g,
                             const float* __restrict__ w_in, const float* __restrict__ w_fu1,
                             const float* __restrict__ w_fu2, float* __restrict__ wT) {
  const int idx = blockIdx.x * 256 + threadIdx.x;   // 96*256 = 24576
  if (idx < 4096) {
    int ci = idx >> 6, o = idx & 63;
    wT[idx] = w_g2l[o * 64 + ci];
  } else if (idx < 8192) {
    int j = idx - 4096; int ci = j >> 6, o = j & 63;
    wT[idx] = w_local[o * 64 + ci];
  } else if (idx < 10240) {
    int j = idx - 8192; int ci = j >> 6, o = j & 63;
    wT[idx] = w_out[o * 32 + ci];
  } else if (idx < 14336) {
    int j = idx - 10240; int ci = j >> 6, o = j & 63;
    wT[idx] = w_l2g[o * 64 + ci];
  } else if (idx < 16384) {
    int j = idx - 14336; int ci = j >> 5, o = j & 31;
    wT[idx] = w_in[o * 64 + ci];
  } else if (idx < 20480) {
    int j = idx - 16384; int ci = j >> 6, o = j & 63;
    wT[idx] = w_fu1[o * 64 + ci];
  } else if (idx < 24576) {
    int j = idx - 20480; int ci = j >> 6, o = j & 63;
    wT[idx] = w_fu2[o * 64 + ci];
  }
}

// ---------------- fused epilogue: scalar weights, zero LDS, 4-deep prefetch -------------
__device__ __forceinline__ void final_l_body(const float* __restrict__ x, float* __restrict__ out,
                                             const float* __restrict__ gT,
                                             const float* __restrict__ lT,
                                             const float* __restrict__ b_local,
                                             const float* __restrict__ b_g2l,
                                             int pblk, int og, int t) {
  const int p4 = pblk * 64 + (t & 63);
  const int hw4 = p4 & 16383;
  const int b = p4 >> 14;
  const float4* xb = (const float4*)x + (size_t)b * 128 * 16384 + hw4;
  float4 acc[16];
#pragma unroll
  for (int o = 0; o < 16; ++o) {
    float bv = b_local[og * 16 + o] + b_g2l[og * 16 + o];
    acc[o] = make_float4(bv, bv, bv, bv);
  }
  float4 g0 = xb[0], g1 = xb[16384], g2 = xb[2 * 16384], g3 = xb[3 * 16384];
  float4 l0 = xb[(size_t)64 * 16384], l1 = xb[(size_t)65 * 16384];
  float4 l2 = xb[(size_t)66 * 16384], l3 = xb[(size_t)67 * 16384];
  for (int ci = 0; ci < 64; ci += 4) {
    float4 cg0 = g0, cg1 = g1, cg2 = g2, cg3 = g3;
    float4 cl0 = l0, cl1 = l1, cl2 = l2, cl3 = l3;
    if (ci < 60) {
      const float4* np = xb + (size_t)(ci + 4) * 16384;
      g0 = np[0]; g1 = np[16384]; g2 = np[2 * 16384]; g3 = np[3 * 16384];
      l0 = np[(size_t)64 * 16384]; l1 = np[(size_t)65 * 16384];
      l2 = np[(size_t)66 * 16384]; l3 = np[(size_t)67 * 16384];
    }
#pragma unroll
    for (int k = 0; k < 4; ++k) {
      float4 xg = (k == 0) ? cg0 : (k == 1) ? cg1 : (k == 2) ? cg2 : cg3;
      float4 xl = (k == 0) ? cl0 : (k == 1) ? cl1 : (k == 2) ? cl2 : cl3;
      const float4* g4 = (const float4*)&gT[(ci + k) * 64 + og * 16];
      const float4* l4 = (const float4*)&lT[(ci + k) * 64 + og * 16];
#pragma unroll
      for (int o4 = 0; o4 < 4; ++o4) {
        float4 a = g4[o4], cw = l4[o4];
        fma4(acc[4 * o4 + 0], a.x, xg); fma4(acc[4 * o4 + 0], cw.x, xl);
        fma4(acc[4 * o4 + 1], a.y, xg); fma4(acc[4 * o4 + 1], cw.y, xl);
        fma4(acc[4 * o4 + 2], a.z, xg); fma4(acc[4 * o4 + 2], cw.z, xl);
        fma4(acc[4 * o4 + 3], a.w, xg); fma4(acc[4 * o4 + 3], cw.w, xl);
      }
    }
  }
  float4* ob = (float4*)out + (size_t)(b * 128 + 64 + og * 16) * 16384 + hw4;
#pragma unroll
  for (int o = 0; o < 16; ++o) ob[(size_t)o * 16384] = acc[o];
}

__device__ __forceinline__ void final_g_body(const float* __restrict__ x,
                                             const float* __restrict__ y_g, const float* __restrict__ y2,
                                             float* __restrict__ out,
                                             const float* __restrict__ oT,
                                             const float* __restrict__ lT,
                                             const float* __restrict__ b_out,
                                             const float* __restrict__ b_l2g,
                                             int pblk, int og, int t) {
  const int p4 = pblk * 64 + (t & 63);
  const int hw4 = p4 & 16383;
  const int b = p4 >> 14;
  const int h = hw4 >> 6;                      // 64 float4 per row
  const int w4 = hw4 & 63;
  const int hw2_4 = ((h & 127) << 5) + (w4 & 31);
  const float4* xb = (const float4*)x + (size_t)(b * 128 + 64) * 16384 + hw4;
  const float4* gb = (const float4*)y_g + (size_t)b * 32 * 16384 + hw4;
  const float4* tb = (const float4*)y2 + (size_t)b * 32 * 4096 + hw2_4;
  float4 acc[16];
#pragma unroll
  for (int o = 0; o < 16; ++o) {
    float bv = b_out[og * 16 + o] + b_l2g[og * 16 + o];
    acc[o] = make_float4(bv, bv, bv, bv);
  }
  // ---- pass 1: s = y_g + y2 (32 channels), 4-channel groups with prefetch ----
  float4 pg0 = gb[0], pg1 = gb[16384], pg2 = gb[2 * 16384], pg3 = gb[3 * 16384];
  float4 pt0 = tb[0], pt1 = tb[4096], pt2 = tb[2 * 4096], pt3 = tb[3 * 4096];
  for (int ci = 0; ci < 32; ci += 4) {
    float4 s0 = add4(pg0, pt0), s1 = add4(pg1, pt1);
    float4 s2 = add4(pg2, pt2), s3 = add4(pg3, pt3);
    if (ci < 28) {
      const float4* gp = gb + (size_t)(ci + 4) * 16384;
      const float4* tp = tb + (size_t)(ci + 4) * 4096;
      pg0 = gp[0]; pg1 = gp[16384]; pg2 = gp[2 * 16384]; pg3 = gp[3 * 16384];
      pt0 = tp[0]; pt1 = tp[4096]; pt2 = tp[2 * 4096]; pt3 = tp[3 * 4096];
    }
#pragma unroll
    for (int k = 0; k < 4; ++k) {
      float4 s = (k == 0) ? s0 : (k == 1) ? s1 : (k == 2) ? s2 : s3;
      const float4* w4p = (const float4*)&oT[(ci + k) * 64 + og * 16];
#pragma unroll
      for (int o4 = 0; o4 < 4; ++o4) {
        float4 a = w4p[o4];
        fma4(acc[4 * o4 + 0], a.x, s);
        fma4(acc[4 * o4 + 1], a.y, s);
        fma4(acc[4 * o4 + 2], a.z, s);
        fma4(acc[4 * o4 + 3], a.w, s);
      }
    }
  }
  // ---- pass 2: x_l (64 channels), 4-channel groups with prefetch ----
  float4 n0 = xb[0], n1 = xb[16384], n2 = xb[2 * 16384], n3 = xb[3 * 16384];
  for (int ci = 0; ci < 64; ci += 4) {
    float4 c0 = n0, c1 = n1, c2 = n2, c3 = n3;
    if (ci < 60) {
      const float4* np = xb + (size_t)(ci + 4) * 16384;
      n0 = np[0]; n1 = np[16384]; n2 = np[2 * 16384]; n3 = np[3 * 16384];
    }
#pragma unroll
    for (int k = 0; k < 4; ++k) {
      float4 xl = (k == 0) ? c0 : (k == 1) ? c1 : (k == 2) ? c2 : c3;
      const float4* w4p = (const float4*)&lT[(ci + k) * 64 + og * 16];
#pragma unroll
      for (int o4 = 0; o4 < 4; ++o4) {
        float4 a = w4p[o4];
        fma4(acc[4 * o4 + 0], a.x, xl);
        fma4(acc[4 * o4 + 1], a.y, xl);
        fma4(acc[4 * o4 + 2], a.z, xl);
        fma4(acc[4 * o4 + 3], a.w, xl);
      }
    }
  }
  float4* ob = (float4*)out + (size_t)(b * 128 + og * 16) * 16384 + hw4;
#pragma unroll
  for (int o = 0; o < 16; ++o) ob[(size_t)o * 16384] = acc[o];
}

__global__ __launch_bounds__(256, 4) void final_fused(const float* __restrict__ x,
                          const float* __restrict__ y_g, const float* __restrict__ y2,
                          const float* __restrict__ wT,
                          const float* __restrict__ b_out, const float* __restrict__ b_l2g,
                          const float* __restrict__ b_local, const float* __restrict__ b_g2l,
                          float* __restrict__ out) {
  const int t = threadIdx.x;
  const int og = __builtin_amdgcn_readfirstlane(t >> 6);   // wave-uniform output group
  const int isL = blockIdx.x & 1;
  const int pblk = blockIdx.x >> 1;
  if (isL)
    final_l_body(x, out, wT, wT + 4096, b_local, b_g2l, pblk, og, t);
  else
    final_g_body(x, y_g, y2, out, wT + 8192, wT + 10240, b_out, b_l2g, pblk, og, t);
}

extern "C" void kernel_launch(void* const* d_in, const int* in_sizes, int n_in,
                              void* d_out, int out_size, void* d_ws, size_t ws_size,
                              hipStream_t stream) {
  (void)in_sizes; (void)n_in; (void)out_size; (void)ws_size;
  const float* x       = (const float*)d_in[0];
  const float* w_local = (const float*)d_in[1];
  const float* b_local = (const float*)d_in[2];
  const float* w_in    = (const float*)d_in[3];
  const float* b_in    = (const float*)d_in[4];
  const float* w_out   = (const float*)d_in[5];
  const float* b_out   = (const float*)d_in[6];
  const float* w_g2l   = (const float*)d_in[7];
  const float* b_g2l   = (const float*)d_in[8];
  const float* w_l2g   = (const float*)d_in[9];
  const float* b_l2g   = (const float*)d_in[10];
  const float* w_fu1   = (const float*)d_in[11];
  const float* b_fu1   = (const float*)d_in[12];
  const float* g_fu1   = (const float*)d_in[13];
  const float* be_fu1  = (const float*)d_in[14];
  const float* w_fu2   = (const float*)d_in[15];
  const float* b_fu2   = (const float*)d_in[16];
  const float* g_fu2   = (const float*)d_in[17];
  const float* be_fu2  = (const float*)d_in[18];
  float* out = (float*)d_out;

  // workspace layout (floats)
  float* ws   = (float*)d_ws;
  float* y_in = ws;                       // 8,388,608
  float* S1   = y_in + 8388608;           // 8,454,144 floats
  float* Z1   = S1 + 8454144;             // 8,454,144 (y_g overlays after Z1 dead)
  float* y_g  = Z1;
  float* S2   = Z1 + 8454144;             // 2,129,920 floats
  float* Z2   = S2 + 2129920;             // 2,129,920 (y2 overlays)
  float* y2   = Z2;
  double* pb1 = (double*)(Z2 + 2129920);  // 4096 doubles (per-slice partials, FU1)
  double* pb2 = pb1 + 4096;               // 4096 doubles (FU2)
  float* wT   = (float*)(pb2 + 4096);     // 24576 floats (transposed weights)

  prep_weights<<<96, 256, 0, stream>>>(w_g2l, w_local, w_out, w_l2g, w_in, w_fu1, w_fu2, wT);
  conv_in_v<<<1024, 256, 0, stream>>>(x, wT + 14336, b_in, y_in);

  // fused forward row transforms (FU1 packed pairs + LFU rows)
  rfft_fused<<<16384 + 8192, 128, 0, stream>>>(y_in, (float2*)S1, (float2*)S2);
  // fused forward column transforms
  cfft_cols_fused<<<1152 + 640, 256, 0, stream>>>((float2*)S1, (float2*)S2);

  // fused spectral convs (scalar weights) + BN stats
  conv_spec_fused<<<516 + 130, 256, 0, stream>>>((const float4*)S1, wT + 16384, b_fu1, (float2*)Z1,
                                                 (const float4*)S2, wT + 20480, b_fu2, (float2*)Z2);
  bn_stats_fused<<<4096, 256, 0, stream>>>(Z1, Z2, pb1, pb2);

  // fused inverse column transforms (bn finalize inlined, bit-identical partial order)
  cfft_inv_fused<<<1152 + 640, 256, 0, stream>>>(Z1, pb1, g_fu1, be_fu1, (float2*)S1,
                                                 Z2, pb2, g_fu2, be_fu2, (float2*)S2);
  // fused inverse row transforms (FU1 packed pairs + FU2 rows)
  irfft_fused<<<16384 + 8192, 128, 0, stream>>>((const float2*)S1, y_g, (const float2*)S2, y2);

  // fused epilogue: even blocks -> global-out path, odd blocks -> local-out path
  final_fused<<<2048, 256, 0, stream>>>(x, y_g, y2, wT, b_out, b_l2g, b_local, b_g2l, out);
}

// Round 15
// 518.426 us; speedup vs baseline: 1.4717x; 1.4717x over previous
//
#include <hip/hip_runtime.h>
#include <math.h>

// FastFourierConvolution: B=4, C=128, H=W=256. Cg=Cl=64, Ci=32.
// FU1: (B,32,256,256) -> rfft2 -> conv64x64+BN+relu -> herm irfft2
// FU2 (LFU): y_in[:,24:32] quadrant-stacked to (B,32,128,128), same pipeline, tiled 2x2.
// R15: byte-exact revert of final_fused to the R13 form (session best, 523.7us).
// R14's 4-deep prefetch spilled (WRITE 588MB, 353us) -- 2-deep is the max this
// accumulator shape tolerates. All other kernels unchanged from R13.

#define PI2 6.283185307179586f

__device__ __forceinline__ void fma4(float4& a, float w, const float4& v) {
  a.x += w * v.x; a.y += w * v.y; a.z += w * v.z; a.w += w * v.w;
}
__device__ __forceinline__ float4 add4(const float4& a, const float4& b) {
  return make_float4(a.x + b.x, a.y + b.y, a.z + b.z, a.w + b.w);
}

// ---------------- FFT core: radix-2 DIT in LDS ----------------
template<int N, int LOG2N>
__device__ __forceinline__ void fft_stages(float* re, float* im, int tid, float sign) {
#pragma unroll
  for (int s = 1; s <= LOG2N; ++s) {
    __syncthreads();
    const int half = 1 << (s - 1);
    const int j = tid & (half - 1);
    const int i1 = ((tid >> (s - 1)) << s) + j;
    const int i2 = i1 + half;
    float ang = sign * (PI2 / (float)(1 << s)) * (float)j;
    float wr, wi;
    __sincosf(ang, &wi, &wr);
    float xr = re[i2], xi = im[i2];
    float vr = xr * wr - xi * wi;
    float vi = xr * wi + xi * wr;
    float ur = re[i1], ui = im[i1];
    re[i1] = ur + vr; im[i1] = ui + vi;
    re[i2] = ur - vr; im[i2] = ui - vi;
  }
  __syncthreads();
}

// ---------------- fused row rfft ----------------
// FU1: 2 real rows packed into 1 complex N=256 FFT (16384 blocks), Hermitian split.
// FU2 (LFU): N=128, 2 rows per block via 64-thread sub-groups.
__global__ void rfft_fused(const float* __restrict__ y_in,
                           float2* __restrict__ S1, float2* __restrict__ S2) {
  __shared__ float re[256], im[256];
  const int t = threadIdx.x;  // 128
  if (blockIdx.x < 16384) {
    const int pr = blockIdx.x;                 // rows 2pr, 2pr+1
    const float* p0 = y_in + (size_t)(2 * pr) * 256;
    const float* p1 = p0 + 256;
    for (int i = t; i < 256; i += 128) {
      int j = __brev((unsigned)i) >> 24;
      re[j] = p0[i];
      im[j] = p1[i];
    }
    fft_stages<256, 8>(re, im, t, -1.f);
    float2* q0 = S1 + (size_t)(2 * pr) * 129;
    float2* q1 = q0 + 129;
    for (int k = t; k <= 128; k += 128) {
      int nk = (256 - k) & 255;
      float zr = re[k], zi = im[k], zrn = re[nk], zin = im[nk];
      q0[k] = make_float2(0.5f * (zr + zrn), 0.5f * (zi - zin));
      q1[k] = make_float2(0.5f * (zi + zin), 0.5f * (zrn - zr));
    }
  } else {
    const int sub = t >> 6, t64 = t & 63;
    const int row = (blockIdx.x - 16384) * 2 + sub;   // 16384 LFU rows
    const int h2 = row & 127;
    const int c2 = (row >> 7) & 31;
    const int b  = row >> 12;
    const int q = c2 >> 3, ch = c2 & 7;
    const int hs = ((q >> 1) << 7) + h2;
    const int ws0 = (q & 1) << 7;
    const float* p = y_in + (((size_t)(b * 32 + 24 + ch) * 256 + hs) * 256 + ws0);
    float* r = &re[sub * 128];
    float* iv = &im[sub * 128];
    for (int i = t64; i < 128; i += 64) {
      int j = __brev((unsigned)i) >> 25;
      r[j] = p[i];
      iv[j] = 0.f;
    }
    fft_stages<128, 7>(r, iv, t64, -1.f);
    float2* qp = S2 + (size_t)row * 65;
    for (int k = t64; k <= 64; k += 64) qp[k] = make_float2(r[k], iv[k]);
  }
}

// ---------------- fused forward column FFT (flat [N][17] shared) ----------------
template<int N, int LOG2N>
__device__ __forceinline__ void cfft_cols_body(float2* __restrict__ data, int Wf, float sign,
                                               int tilesPerImg, int bid,
                                               float* __restrict__ re, float* __restrict__ im) {
  const int TW = 16;
  const int img = bid / tilesPerImg;
  const int k0 = (bid % tilesPerImg) * TW;
  const int cols = min(TW, Wf - k0);
  float2* base = data + (size_t)img * N * Wf + k0;
  const int t = threadIdx.x;
  const int c = t & (TW - 1);
  const int g = t >> 4;
  const bool act = (c < cols);
  for (int r = g; r < N; r += 16) {
    float2 v;
    if (act) v = base[(size_t)r * Wf + c];
    int j = __brev((unsigned)r) >> (32 - LOG2N);
    if (act) { re[j * 17 + c] = v.x; im[j * 17 + c] = v.y; }
  }
#pragma unroll
  for (int s = 1; s <= LOG2N; ++s) {
    __syncthreads();
    const int half = 1 << (s - 1);
    for (int bf = g; bf < N / 2; bf += 16) {
      if (!act) continue;
      const int j = bf & (half - 1);
      const int i1 = ((bf >> (s - 1)) << s) + j;
      const int i2 = i1 + half;
      float ang = sign * (PI2 / (float)(1 << s)) * (float)j;
      float wr, wi;
      __sincosf(ang, &wi, &wr);
      float xr = re[i2 * 17 + c], xi = im[i2 * 17 + c];
      float vr = xr * wr - xi * wi;
      float vi = xr * wi + xi * wr;
      float ur = re[i1 * 17 + c], ui = im[i1 * 17 + c];
      re[i1 * 17 + c] = ur + vr; im[i1 * 17 + c] = ui + vi;
      re[i2 * 17 + c] = ur - vr; im[i2 * 17 + c] = ui - vi;
    }
  }
  __syncthreads();
  for (int r = g; r < N; r += 16) {
    if (act) base[(size_t)r * Wf + c] = make_float2(re[r * 17 + c], im[r * 17 + c]);
  }
}

__global__ void cfft_cols_fused(float2* __restrict__ d1, float2* __restrict__ d2) {
  __shared__ float re[256 * 17], im[256 * 17];
  if (blockIdx.x < 1152)
    cfft_cols_body<256, 8>(d1, 129, -1.f, 9, blockIdx.x, re, im);
  else
    cfft_cols_body<128, 7>(d2, 65, -1.f, 5, blockIdx.x - 1152, re, im);
}

// ---------------- fused BN(finalize inlined)+relu+symmetrize + inverse column FFT --------
template<int N, int LOG2N>
__device__ __forceinline__ void cfft_inv_body(const float* __restrict__ Z,
                            const double* __restrict__ pb, const float* __restrict__ gamma,
                            const float* __restrict__ beta, int n,
                            float2* __restrict__ T, int Wf, int tilesPerImg, int chs, int bid,
                            float* __restrict__ re, float* __restrict__ im) {
  const int TW = 16;
  const int img = bid / tilesPerImg;    // b*32 + cc
  const int b = img >> 5, cc = img & 31;
  const int k0 = (bid % tilesPerImg) * TW;
  const int cols = min(TW, Wf - k0);
  const int t = threadIdx.x;
  const int c = t & (TW - 1);
  const int g = t >> 4;
  const bool act = (c < cols);
  const int kk = k0 + c;
  // inlined bn_finalize: sum the 32 per-slice partials in the exact order the old kernel used
  double s_r = 0.0, q_r = 0.0, s_i = 0.0, q_i = 0.0;
  for (int i = 0; i < 32; ++i) {
    s_r += pb[2 * (cc * 32 + i)];
    q_r += pb[2 * (cc * 32 + i) + 1];
    s_i += pb[2 * ((cc + 32) * 32 + i)];
    q_i += pb[2 * ((cc + 32) * 32 + i) + 1];
  }
  double mu_r = s_r / (double)n, var_r = q_r / (double)n - mu_r * mu_r;
  double mu_i = s_i / (double)n, var_i = q_i / (double)n - mu_i * mu_i;
  float rs_r = (float)(1.0 / sqrt(var_r + 1e-5));
  float rs_i = (float)(1.0 / sqrt(var_i + 1e-5));
  const float scr = gamma[cc] * rs_r;
  const float sfr = beta[cc] - (float)mu_r * scr;
  const float sci = gamma[cc + 32] * rs_i;
  const float sfi = beta[cc + 32] - (float)mu_i * sci;
  const float* Zr = Z + (size_t)cc * chs + (size_t)b * N * Wf;
  const float* Zi = Z + (size_t)(cc + 32) * chs + (size_t)b * N * Wf;
  const bool edge = (kk == 0 || kk == Wf - 1);
  for (int r = g; r < N; r += 16) {
    float vr = 0.f, vi = 0.f;
    if (act) {
      size_t p = (size_t)r * Wf + kk;
      float yr = fmaxf(Zr[p] * scr + sfr, 0.f);
      float yi = fmaxf(Zi[p] * sci + sfi, 0.f);
      if (edge) {
        int rm = (N - r) & (N - 1);
        size_t pm = (size_t)rm * Wf + kk;
        float yr2 = fmaxf(Zr[pm] * scr + sfr, 0.f);
        float yi2 = fmaxf(Zi[pm] * sci + sfi, 0.f);
        yr = 0.5f * (yr + yr2);
        yi = 0.5f * (yi - yi2);
      }
      vr = yr; vi = yi;
    }
    int j = __brev((unsigned)r) >> (32 - LOG2N);
    if (act) { re[j * 17 + c] = vr; im[j * 17 + c] = vi; }
  }
#pragma unroll
  for (int s = 1; s <= LOG2N; ++s) {
    __syncthreads();
    const int half = 1 << (s - 1);
    for (int bf = g; bf < N / 2; bf += 16) {
      if (!act) continue;
      const int jq = bf & (half - 1);
      const int i1 = ((bf >> (s - 1)) << s) + jq;
      const int i2 = i1 + half;
      float ang = (PI2 / (float)(1 << s)) * (float)jq;
      float wr, wi;
      __sincosf(ang, &wi, &wr);
      float xr = re[i2 * 17 + c], xi = im[i2 * 17 + c];
      float pr = xr * wr - xi * wi;
      float pi = xr * wi + xi * wr;
      float ur = re[i1 * 17 + c], ui = im[i1 * 17 + c];
      re[i1 * 17 + c] = ur + pr; im[i1 * 17 + c] = ui + pi;
      re[i2 * 17 + c] = ur - pr; im[i2 * 17 + c] = ui - pi;
    }
  }
  __syncthreads();
  float2* base = T + (size_t)img * N * Wf + k0;
  for (int r = g; r < N; r += 16)
    if (act) base[(size_t)r * Wf + c] = make_float2(re[r * 17 + c], im[r * 17 + c]);
}

__global__ void cfft_inv_fused(const float* __restrict__ Z1, const double* __restrict__ pb1,
                               const float* __restrict__ g1, const float* __restrict__ be1,
                               float2* __restrict__ T1,
                               const float* __restrict__ Z2, const double* __restrict__ pb2,
                               const float* __restrict__ g2, const float* __restrict__ be2,
                               float2* __restrict__ T2) {
  __shared__ float re[256 * 17], im[256 * 17];
  if (blockIdx.x < 1152)
    cfft_inv_body<256, 8>(Z1, pb1, g1, be1, 132096, T1, 129, 9, 132096, blockIdx.x, re, im);
  else
    cfft_inv_body<128, 7>(Z2, pb2, g2, be2, 33280, T2, 65, 5, 33280, blockIdx.x - 1152, re, im);
}

// ---------------- fused row irfft ----------------
// FU1: 2 Hermitian spectra packed into 1 complex inverse N=256 FFT (16384 blocks).
// FU2: N=128, 2 rows per block via 64-thread sub-groups.
__global__ void irfft_fused(const float2* __restrict__ T1, float* __restrict__ y_g,
                            const float2* __restrict__ T2, float* __restrict__ y2) {
  __shared__ float re[256], im[256];
  const int t = threadIdx.x;  // 128
  if (blockIdx.x < 16384) {
    const int pr = blockIdx.x;                 // rows 2pr, 2pr+1
    const float2* p0 = T1 + (size_t)(2 * pr) * 129;
    const float2* p1 = p0 + 129;
    for (int i = t; i < 256; i += 128) {
      float zr, zi;
      if (i <= 128) {
        float2 A = p0[i], Bv = p1[i];
        zr = A.x - Bv.y; zi = A.y + Bv.x;          // Z = A + iB
      } else {
        int nk = 256 - i;
        float2 A = p0[nk], Bv = p1[nk];
        zr = A.x + Bv.y; zi = Bv.x - A.y;          // Z = conj(A) + i conj(B)
      }
      int j = __brev((unsigned)i) >> 24;
      re[j] = zr; im[j] = zi;
    }
    fft_stages<256, 8>(re, im, t, 1.f);
    float* q0 = y_g + (size_t)(2 * pr) * 256;
    float* q1 = q0 + 256;
    for (int i = t; i < 256; i += 128) {
      q0[i] = re[i] * (1.f / 65536.f);
      q1[i] = im[i] * (1.f / 65536.f);
    }
  } else {
    const int sub = t >> 6, t64 = t & 63;
    const int row = (blockIdx.x - 16384) * 2 + sub;   // 16384 FU2 rows
    const float2* p = T2 + (size_t)row * 65;
    float* r = &re[sub * 128];
    float* iv = &im[sub * 128];
    for (int i = t64; i < 128; i += 64) {
      float2 v;
      if (i <= 64) v = p[i];
      else { v = p[128 - i]; v.y = -v.y; }
      int j = __brev((unsigned)i) >> 25;
      r[j] = v.x; iv[j] = v.y;
    }
    fft_stages<128, 7>(r, iv, t64, 1.f);
    float* q = y2 + (size_t)row * 128;
    for (int i = t64; i < 128; i += 64) q[i] = r[i] * (1.f / 16384.f);
  }
}

// ---------------- y_in = w_in(32x64) @ x[:, :64] + b_in: scalar weights, zero LDS --------
__global__ __launch_bounds__(256, 4) void conv_in_v(const float* __restrict__ x,
                          const float* __restrict__ wT,   // inT[ci*32+o]
                          const float* __restrict__ bias, float* __restrict__ y) {
  const int t = threadIdx.x;
  const int og = __builtin_amdgcn_readfirstlane(t >> 6);   // 0..3, wave-uniform
  const int p4 = blockIdx.x * 64 + (t & 63);   // 65536 float4-pixels
  const int hw4 = p4 & 16383;
  const int b = p4 >> 14;
  const float4* xb = (const float4*)x + (size_t)b * 128 * 16384 + hw4;
  float4 acc[8];
#pragma unroll
  for (int o = 0; o < 8; ++o) { float bv = bias[og * 8 + o]; acc[o] = make_float4(bv, bv, bv, bv); }
  float4 n0 = xb[0], n1 = xb[16384], n2 = xb[2 * 16384], n3 = xb[3 * 16384];
  for (int ci = 0; ci < 64; ci += 4) {
    float4 c0 = n0, c1 = n1, c2 = n2, c3 = n3;
    if (ci < 60) {
      const float4* np = xb + (size_t)(ci + 4) * 16384;
      n0 = np[0]; n1 = np[16384]; n2 = np[2 * 16384]; n3 = np[3 * 16384];
    }
#pragma unroll
    for (int k = 0; k < 4; ++k) {
      float4 v = (k == 0) ? c0 : (k == 1) ? c1 : (k == 2) ? c2 : c3;
      const float4* w4p = (const float4*)&wT[(ci + k) * 32 + og * 8];
      float4 a = w4p[0], c = w4p[1];
      fma4(acc[0], a.x, v); fma4(acc[1], a.y, v); fma4(acc[2], a.z, v); fma4(acc[3], a.w, v);
      fma4(acc[4], c.x, v); fma4(acc[5], c.y, v); fma4(acc[6], c.z, v); fma4(acc[7], c.w, v);
    }
  }
  float4* yb = (float4*)y + (size_t)(b * 32 + og * 8) * 16384 + hw4;
#pragma unroll
  for (int o = 0; o < 8; ++o) yb[(size_t)o * 16384] = acc[o];
}

// ---------------- spectral conv: scalar weights, zero LDS ----------------
template<int B_, int H_, int Wf_>
__device__ __forceinline__ void conv_spec_body(const float4* __restrict__ S4,
                            const float* __restrict__ wT,   // [ci*64+o], ci incl imag rows
                            const float* __restrict__ bias,
                            float2* __restrict__ Z2, int bid, int og, int t) {
  constexpr int PP = H_ * Wf_ / 2;      // complex pairs per (b,ci) plane
  constexpr int CHS2 = B_ * PP;         // pairs per out-channel
  const int j2 = bid * 128 + (t & 127);         // global pair index
  const int b = j2 / PP;
  const int jp = j2 - b * PP;
  float2 acc[32];
#pragma unroll
  for (int o = 0; o < 32; ++o) { float bv = bias[og * 32 + o]; acc[o] = make_float2(bv, bv); }
  const float4* sp = S4 + (size_t)(b * 32) * PP + jp;
  float4 nv = sp[0];
  for (int ci = 0; ci < 32; ++ci) {
    float4 sv = nv;                      // two complex: (x,y) (z,w)
    if (ci < 31) nv = sp[(size_t)(ci + 1) * PP];
    const float4* wr4 = (const float4*)&wT[ci * 64 + og * 32];
    const float4* wi4 = (const float4*)&wT[(ci + 32) * 64 + og * 32];
#pragma unroll
    for (int o4 = 0; o4 < 8; ++o4) {
      float4 a = wr4[o4], c = wi4[o4];
      acc[4 * o4 + 0].x += a.x * sv.x + c.x * sv.y;  acc[4 * o4 + 0].y += a.x * sv.z + c.x * sv.w;
      acc[4 * o4 + 1].x += a.y * sv.x + c.y * sv.y;  acc[4 * o4 + 1].y += a.y * sv.z + c.y * sv.w;
      acc[4 * o4 + 2].x += a.z * sv.x + c.z * sv.y;  acc[4 * o4 + 2].y += a.z * sv.z + c.z * sv.w;
      acc[4 * o4 + 3].x += a.w * sv.x + c.w * sv.y;  acc[4 * o4 + 3].y += a.w * sv.z + c.w * sv.w;
    }
  }
#pragma unroll
  for (int o = 0; o < 32; ++o) Z2[(size_t)(og * 32 + o) * CHS2 + j2] = acc[o];
}

__global__ __launch_bounds__(256, 4) void conv_spec_fused(
    const float4* __restrict__ S1, const float* __restrict__ w1T, const float* __restrict__ b1,
    float2* __restrict__ Z1,
    const float4* __restrict__ S2, const float* __restrict__ w2T, const float* __restrict__ b2,
    float2* __restrict__ Z2) {
  const int t = threadIdx.x;
  const int og = __builtin_amdgcn_readfirstlane(t >> 7);   // 0/1, wave-uniform
  if (blockIdx.x < 516)
    conv_spec_body<4, 256, 129>(S1, w1T, b1, Z1, blockIdx.x, og, t);
  else
    conv_spec_body<4, 128, 65>(S2, w2T, b2, Z2, blockIdx.x - 516, og, t);
}

// ---------------- BN stats fused (FU1: 2048 blocks, FU2: 2048 blocks) ----------------
__global__ void bn_stats_fused(const float* __restrict__ Z1, const float* __restrict__ Z2,
                               double* __restrict__ pb1, double* __restrict__ pb2) {
  int bid = blockIdx.x;
  const float* Z; double* pb; int chunk;
  if (bid < 2048) { Z = Z1; pb = pb1; chunk = 4128; }
  else { bid -= 2048; Z = Z2; pb = pb2; chunk = 1040; }
  const int c = bid >> 5;
  const int sl = bid & 31;
  const float* p = Z + (size_t)c * ((size_t)chunk * 32) + (size_t)sl * chunk;
  double s = 0.0, s2 = 0.0;
  for (int i = threadIdx.x; i < chunk; i += 256) {
    float v = p[i];
    s += v;
    s2 += (double)v * (double)v;
  }
  __shared__ double sh[256], sh2[256];
  sh[threadIdx.x] = s; sh2[threadIdx.x] = s2;
  __syncthreads();
  for (int off = 128; off > 0; off >>= 1) {
    if (threadIdx.x < off) { sh[threadIdx.x] += sh[threadIdx.x + off]; sh2[threadIdx.x] += sh2[threadIdx.x + off]; }
    __syncthreads();
  }
  if (threadIdx.x == 0) { pb[2 * bid] = sh[0]; pb[2 * bid + 1] = sh2[0]; }
}

// ---------------- weight transpose for scalar-load kernels ----------------
// wT layout (floats): [0..4095] g2l_T, [4096..8191] local_T, [8192..10239] out_T,
// [10240..14335] l2g_T, [14336..16383] in_T[ci*32+o], [16384..20479] fu1_T[ci*64+o],
// [20480..24575] fu2_T[ci*64+o].
__global__ void prep_weights(const float* __restrict__ w_g2l, const float* __restrict__ w_local,
                             const float* __restrict__ w_out, const float* __restrict__ w_l2g,
                             const float* __restrict__ w_in, const float* __restrict__ w_fu1,
                             const float* __restrict__ w_fu2, float* __restrict__ wT) {
  const int idx = blockIdx.x * 256 + threadIdx.x;   // 96*256 = 24576
  if (idx < 4096) {
    int ci = idx >> 6, o = idx & 63;
    wT[idx] = w_g2l[o * 64 + ci];
  } else if (idx < 8192) {
    int j = idx - 4096; int ci = j >> 6, o = j & 63;
    wT[idx] = w_local[o * 64 + ci];
  } else if (idx < 10240) {
    int j = idx - 8192; int ci = j >> 6, o = j & 63;
    wT[idx] = w_out[o * 32 + ci];
  } else if (idx < 14336) {
    int j = idx - 10240; int ci = j >> 6, o = j & 63;
    wT[idx] = w_l2g[o * 64 + ci];
  } else if (idx < 16384) {
    int j = idx - 14336; int ci = j >> 5, o = j & 31;
    wT[idx] = w_in[o * 64 + ci];
  } else if (idx < 20480) {
    int j = idx - 16384; int ci = j >> 6, o = j & 63;
    wT[idx] = w_fu1[o * 64 + ci];
  } else if (idx < 24576) {
    int j = idx - 20480; int ci = j >> 6, o = j & 63;
    wT[idx] = w_fu2[o * 64 + ci];
  }
}

// ---------------- fused epilogue: scalar (SGPR) weights, zero LDS (R13-proven) ----------
__device__ __forceinline__ void final_l_body(const float* __restrict__ x, float* __restrict__ out,
                                             const float* __restrict__ gT,
                                             const float* __restrict__ lT,
                                             const float* __restrict__ b_local,
                                             const float* __restrict__ b_g2l,
                                             int pblk, int og, int t) {
  const int p4 = pblk * 64 + (t & 63);
  const int hw4 = p4 & 16383;
  const int b = p4 >> 14;
  const float4* xb = (const float4*)x + (size_t)b * 128 * 16384 + hw4;
  float4 acc[16];
#pragma unroll
  for (int o = 0; o < 16; ++o) {
    float bv = b_local[og * 16 + o] + b_g2l[og * 16 + o];
    acc[o] = make_float4(bv, bv, bv, bv);
  }
  float4 g0 = xb[0], g1 = xb[16384];
  float4 l0 = xb[(size_t)64 * 16384], l1 = xb[(size_t)65 * 16384];
  for (int ci = 0; ci < 64; ci += 2) {
    float4 cg0 = g0, cg1 = g1, cl0 = l0, cl1 = l1;
    if (ci < 62) {
      const float4* np = xb + (size_t)(ci + 2) * 16384;
      g0 = np[0]; g1 = np[16384];
      l0 = np[(size_t)64 * 16384]; l1 = np[(size_t)65 * 16384];
    }
#pragma unroll
    for (int k = 0; k < 2; ++k) {
      float4 xg = k ? cg1 : cg0;
      float4 xl = k ? cl1 : cl0;
      const float4* g4 = (const float4*)&gT[(ci + k) * 64 + og * 16];
      const float4* l4 = (const float4*)&lT[(ci + k) * 64 + og * 16];
#pragma unroll
      for (int o4 = 0; o4 < 4; ++o4) {
        float4 a = g4[o4], cw = l4[o4];
        fma4(acc[4 * o4 + 0], a.x, xg); fma4(acc[4 * o4 + 0], cw.x, xl);
        fma4(acc[4 * o4 + 1], a.y, xg); fma4(acc[4 * o4 + 1], cw.y, xl);
        fma4(acc[4 * o4 + 2], a.z, xg); fma4(acc[4 * o4 + 2], cw.z, xl);
        fma4(acc[4 * o4 + 3], a.w, xg); fma4(acc[4 * o4 + 3], cw.w, xl);
      }
    }
  }
  float4* ob = (float4*)out + (size_t)(b * 128 + 64 + og * 16) * 16384 + hw4;
#pragma unroll
  for (int o = 0; o < 16; ++o) ob[(size_t)o * 16384] = acc[o];
}

__device__ __forceinline__ void final_g_body(const float* __restrict__ x,
                                             const float* __restrict__ y_g, const float* __restrict__ y2,
                                             float* __restrict__ out,
                                             const float* __restrict__ oT,
                                             const float* __restrict__ lT,
                                             const float* __restrict__ b_out,
                                             const float* __restrict__ b_l2g,
                                             int pblk, int og, int t) {
  const int p4 = pblk * 64 + (t & 63);
  const int hw4 = p4 & 16383;
  const int b = p4 >> 14;
  const int h = hw4 >> 6;                      // 64 float4 per row
  const int w4 = hw4 & 63;
  const int hw2_4 = ((h & 127) << 5) + (w4 & 31);
  const float4* xb = (const float4*)x + (size_t)(b * 128 + 64) * 16384 + hw4;
  const float4* gb = (const float4*)y_g + (size_t)b * 32 * 16384 + hw4;
  const float4* tb = (const float4*)y2 + (size_t)b * 32 * 4096 + hw2_4;
  float4 acc[16];
#pragma unroll
  for (int o = 0; o < 16; ++o) {
    float bv = b_out[og * 16 + o] + b_l2g[og * 16 + o];
    acc[o] = make_float4(bv, bv, bv, bv);
  }
  // ---- pass 1: s = y_g + y2 (32 channels), 2-channel groups with prefetch ----
  float4 pg0 = gb[0], pg1 = gb[16384];
  float4 pt0 = tb[0], pt1 = tb[4096];
  for (int ci = 0; ci < 32; ci += 2) {
    float4 s0 = add4(pg0, pt0), s1 = add4(pg1, pt1);
    if (ci < 30) {
      const float4* gp = gb + (size_t)(ci + 2) * 16384;
      const float4* tp = tb + (size_t)(ci + 2) * 4096;
      pg0 = gp[0]; pg1 = gp[16384];
      pt0 = tp[0]; pt1 = tp[4096];
    }
#pragma unroll
    for (int k = 0; k < 2; ++k) {
      float4 s = k ? s1 : s0;
      const float4* w4p = (const float4*)&oT[(ci + k) * 64 + og * 16];
#pragma unroll
      for (int o4 = 0; o4 < 4; ++o4) {
        float4 a = w4p[o4];
        fma4(acc[4 * o4 + 0], a.x, s);
        fma4(acc[4 * o4 + 1], a.y, s);
        fma4(acc[4 * o4 + 2], a.z, s);
        fma4(acc[4 * o4 + 3], a.w, s);
      }
    }
  }
  // ---- pass 2: x_l (64 channels), 4-channel groups with prefetch ----
  float4 n0 = xb[0], n1 = xb[16384], n2 = xb[2 * 16384], n3 = xb[3 * 16384];
  for (int ci = 0; ci < 64; ci += 4) {
    float4 c0 = n0, c1 = n1, c2 = n2, c3 = n3;
    if (ci < 60) {
      const float4* np = xb + (size_t)(ci + 4) * 16384;
      n0 = np[0]; n1 = np[16384]; n2 = np[2 * 16384]; n3 = np[3 * 16384];
    }
#pragma unroll
    for (int k = 0; k < 4; ++k) {
      float4 xl = (k == 0) ? c0 : (k == 1) ? c1 : (k == 2) ? c2 : c3;
      const float4* w4p = (const float4*)&lT[(ci + k) * 64 + og * 16];
#pragma unroll
      for (int o4 = 0; o4 < 4; ++o4) {
        float4 a = w4p[o4];
        fma4(acc[4 * o4 + 0], a.x, xl);
        fma4(acc[4 * o4 + 1], a.y, xl);
        fma4(acc[4 * o4 + 2], a.z, xl);
        fma4(acc[4 * o4 + 3], a.w, xl);
      }
    }
  }
  float4* ob = (float4*)out + (size_t)(b * 128 + og * 16) * 16384 + hw4;
#pragma unroll
  for (int o = 0; o < 16; ++o) ob[(size_t)o * 16384] = acc[o];
}

__global__ __launch_bounds__(256, 4) void final_fused(const float* __restrict__ x,
                          const float* __restrict__ y_g, const float* __restrict__ y2,
                          const float* __restrict__ wT,
                          const float* __restrict__ b_out, const float* __restrict__ b_l2g,
                          const float* __restrict__ b_local, const float* __restrict__ b_g2l,
                          float* __restrict__ out) {
  const int t = threadIdx.x;
  const int og = __builtin_amdgcn_readfirstlane(t >> 6);   // wave-uniform output group
  const int isL = blockIdx.x & 1;
  const int pblk = blockIdx.x >> 1;
  if (isL)
    final_l_body(x, out, wT, wT + 4096, b_local, b_g2l, pblk, og, t);
  else
    final_g_body(x, y_g, y2, out, wT + 8192, wT + 10240, b_out, b_l2g, pblk, og, t);
}

extern "C" void kernel_launch(void* const* d_in, const int* in_sizes, int n_in,
                              void* d_out, int out_size, void* d_ws, size_t ws_size,
                              hipStream_t stream) {
  (void)in_sizes; (void)n_in; (void)out_size; (void)ws_size;
  const float* x       = (const float*)d_in[0];
  const float* w_local = (const float*)d_in[1];
  const float* b_local = (const float*)d_in[2];
  const float* w_in    = (const float*)d_in[3];
  const float* b_in    = (const float*)d_in[4];
  const float* w_out   = (const float*)d_in[5];
  const float* b_out   = (const float*)d_in[6];
  const float* w_g2l   = (const float*)d_in[7];
  const float* b_g2l   = (const float*)d_in[8];
  const float* w_l2g   = (const float*)d_in[9];
  const float* b_l2g   = (const float*)d_in[10];
  const float* w_fu1   = (const float*)d_in[11];
  const float* b_fu1   = (const float*)d_in[12];
  const float* g_fu1   = (const float*)d_in[13];
  const float* be_fu1  = (const float*)d_in[14];
  const float* w_fu2   = (const float*)d_in[15];
  const float* b_fu2   = (const float*)d_in[16];
  const float* g_fu2   = (const float*)d_in[17];
  const float* be_fu2  = (const float*)d_in[18];
  float* out = (float*)d_out;

  // workspace layout (floats)
  float* ws   = (float*)d_ws;
  float* y_in = ws;                       // 8,388,608
  float* S1   = y_in + 8388608;           // 8,454,144 floats
  float* Z1   = S1 + 8454144;             // 8,454,144 (y_g overlays after Z1 dead)
  float* y_g  = Z1;
  float* S2   = Z1 + 8454144;             // 2,129,920 floats
  float* Z2   = S2 + 2129920;             // 2,129,920 (y2 overlays)
  float* y2   = Z2;
  double* pb1 = (double*)(Z2 + 2129920);  // 4096 doubles (per-slice partials, FU1)
  double* pb2 = pb1 + 4096;               // 4096 doubles (FU2)
  float* wT   = (float*)(pb2 + 4096);     // 24576 floats (transposed weights)

  prep_weights<<<96, 256, 0, stream>>>(w_g2l, w_local, w_out, w_l2g, w_in, w_fu1, w_fu2, wT);
  conv_in_v<<<1024, 256, 0, stream>>>(x, wT + 14336, b_in, y_in);

  // fused forward row transforms (FU1 packed pairs + LFU rows)
  rfft_fused<<<16384 + 8192, 128, 0, stream>>>(y_in, (float2*)S1, (float2*)S2);
  // fused forward column transforms
  cfft_cols_fused<<<1152 + 640, 256, 0, stream>>>((float2*)S1, (float2*)S2);

  // fused spectral convs (scalar weights) + BN stats
  conv_spec_fused<<<516 + 130, 256, 0, stream>>>((const float4*)S1, wT + 16384, b_fu1, (float2*)Z1,
                                                 (const float4*)S2, wT + 20480, b_fu2, (float2*)Z2);
  bn_stats_fused<<<4096, 256, 0, stream>>>(Z1, Z2, pb1, pb2);

  // fused inverse column transforms (bn finalize inlined, bit-identical partial order)
  cfft_inv_fused<<<1152 + 640, 256, 0, stream>>>(Z1, pb1, g_fu1, be_fu1, (float2*)S1,
                                                 Z2, pb2, g_fu2, be_fu2, (float2*)S2);
  // fused inverse row transforms (FU1 packed pairs + FU2 rows)
  irfft_fused<<<16384 + 8192, 128, 0, stream>>>((const float2*)S1, y_g, (const float2*)S2, y2);

  // fused epilogue: even blocks -> global-out path, odd blocks -> local-out path
  final_fused<<<2048, 256, 0, stream>>>(x, y_g, y2, wT, b_out, b_l2g, b_local, b_g2l, out);
}